// Round 7
// baseline (1359.518 us; speedup 1.0000x reference)
//
#include <hip/hip_runtime.h>
#include <cstddef>

typedef short bfx8 __attribute__((ext_vector_type(8)));
typedef float f32x4 __attribute__((ext_vector_type(4)));

#define BATCH   4096
#define DXP     32
#define NSTEPS  100
#define NE      16      // batch elements per block
#define NWAVE   16      // waves per block (block = 1024)
#define KS      264     // hidden A-buffer row stride (bf16 elems)
#define XKS     104     // x A-buffer row stride (bf16 elems, 16B-aligned rows)
#define XS      100     // xsF/gbuf row stride in floats
#define PIO2F   1.57079632679489662f

__device__ __forceinline__ unsigned short f2bf(float v){
    unsigned u = __float_as_uint(v);
    u += 0x7FFFu + ((u >> 16) & 1u);          // RNE
    return (unsigned short)(u >> 16);
}
__device__ __forceinline__ float bf2f(unsigned short h){
    return __uint_as_float(((unsigned)h) << 16);
}
// truncation split: hi = top 16 bits, lo = RNE(v - hi).
__device__ __forceinline__ void split_tr(float v, short& hi, short& lo){
    const unsigned u = __float_as_uint(v);
    hi = (short)(u >> 16);
    lo = (short)f2bf(v - __uint_as_float(u & 0xFFFF0000u));
}
// fast tanh (smooth p-path only)
__device__ __forceinline__ float fast_tanh(float x){
    const float e2 = __expf(2.0f * x);
    return 1.0f - __fdividef(2.0f, e2 + 1.0f);
}
// small-angle sin/cos (|x| <~ 0.8 here; Taylor, err < 1e-7, no range reduction)
__device__ __forceinline__ float poly_sin(float x){
    const float x2 = x*x;
    return x*(1.0f + x2*(-1.66666667e-1f + x2*(8.33333333e-3f + x2*(-1.98412698e-4f))));
}
__device__ __forceinline__ float poly_cos(float x){
    const float x2 = x*x;
    return 1.0f + x2*(-0.5f + x2*(4.16666667e-2f + x2*(-1.38888889e-3f + x2*2.48015873e-5f)));
}

// =====================================================================
// Prep: W [T][K][N] fp32 -> fragment-major split-bf16 (unchanged layout)
// =====================================================================
__global__ __launch_bounds__(256)
void prep_frag_n256(const float* __restrict__ in, short* __restrict__ out, int K)
{
    const int KC = K >> 5;
    int b = blockIdx.x;                 // t*KC*4 + kc*4 + q
    const int q = b & 3; b >>= 2;
    const int kc = b % KC, t = b / KC;
    const int n = threadIdx.x;
    const int jt = n >> 4, m = n & 15;
    bfx8 hv, lv;
    #pragma unroll
    for (int i = 0; i < 8; ++i) {
        const int k = kc*32 + q*8 + i;
        const float v = in[((size_t)t*K + k)*256 + n];
        const unsigned short h = f2bf(v);
        hv[i] = (short)h;
        lv[i] = (short)f2bf(v - bf2f(h));
    }
    const size_t base = ((size_t)(t*16 + jt)*KC + kc)*1024 + (q*16 + m)*8;
    *(bfx8*)(out + base)       = hv;
    *(bfx8*)(out + base + 512) = lv;
}

__global__ __launch_bounds__(128)
void prep_frag_n96(const float* __restrict__ in, short* __restrict__ out)
{
    int b = blockIdx.x;                 // t*32 + kc*4 + q
    const int q = b & 3; b >>= 2;
    const int kc = b & 7, t = b >> 3;
    const int n = threadIdx.x;
    if (n >= 96) return;
    const int jt = n >> 4, m = n & 15;
    bfx8 hv, lv;
    #pragma unroll
    for (int i = 0; i < 8; ++i) {
        const int k = kc*32 + q*8 + i;
        const float v = in[((size_t)t*256 + k)*96 + n];
        const unsigned short h = f2bf(v);
        hv[i] = (short)h;
        lv[i] = (short)f2bf(v - bf2f(h));
    }
    const size_t base = ((size_t)(t*6 + jt)*8 + kc)*1024 + (q*16 + m)*8;
    *(bfx8*)(out + base)       = hv;
    *(bfx8*)(out + base + 512) = lv;
}

// =====================================================================
// Hidden layer: 16m x 256j, K = KC*32, input stride IS, fast-tanh,
// trunc-split out. Wave w owns j-tile w. B preload before barrier.
// =====================================================================
template<int KC, int IS>
__device__ __forceinline__ void layer_hidden(
    const short* __restrict__ Wf, const float* __restrict__ bias,
    const short* __restrict__ inH, const short* __restrict__ inL,
    short* __restrict__ outH, short* __restrict__ outL,
    int lane, int wid)
{
    const int m = lane & 15, q = lane >> 4;
    const short* wb = Wf + (size_t)wid*KC*1024 + lane*8;

    bfx8 bh[KC], bl[KC];
    #pragma unroll
    for (int kc = 0; kc < KC; ++kc) {
        bh[kc] = *(const bfx8*)(wb + (size_t)kc*1024);
        bl[kc] = *(const bfx8*)(wb + (size_t)kc*1024 + 512);
    }
    const int cj = wid*16 + m;
    const float bv = bias[cj];

    f32x4 acc0 = (f32x4){0.f,0.f,0.f,0.f};
    f32x4 acc1 = (f32x4){0.f,0.f,0.f,0.f};

    __syncthreads();   // in-buffer written; out-buffer's prior readers done

    const short* aph = inH + m*IS + q*8;
    const short* apl = inL + m*IS + q*8;

    #pragma unroll
    for (int kc = 0; kc < KC; ++kc) {
        const bfx8 ah = *(const bfx8*)(aph + kc*32);
        const bfx8 al = *(const bfx8*)(apl + kc*32);
        acc0 = __builtin_amdgcn_mfma_f32_16x16x32_bf16(ah, bh[kc], acc0, 0, 0, 0);
        acc1 = __builtin_amdgcn_mfma_f32_16x16x32_bf16(al, bh[kc], acc1, 0, 0, 0);
        acc1 = __builtin_amdgcn_mfma_f32_16x16x32_bf16(ah, bl[kc], acc1, 0, 0, 0);
    }
    #pragma unroll
    for (int r = 0; r < 4; ++r) {
        const float v = fast_tanh(acc0[r] + acc1[r] + bv);
        short h, l; split_tr(v, h, l);
        const int row = q*4 + r;
        outH[row*KS + cj] = h;
        outL[row*KS + cj] = l;
    }
}

// =====================================================================
// pMLP layer2 fused with pW3 dot (K=256, fragment layout, 16 jtiles).
// =====================================================================
__device__ __forceinline__ void p_l2_dot(
    const short* __restrict__ Wf,
    const float* __restrict__ pb2, const float* __restrict__ pW3,
    const short* __restrict__ inH, const short* __restrict__ inL,
    float* __restrict__ sPpart, int lane, int wid)
{
    const int m = lane & 15, q = lane >> 4;
    const short* wb = Wf + (size_t)wid*8*1024 + lane*8;

    bfx8 bh[8], bl[8];
    #pragma unroll
    for (int kc = 0; kc < 8; ++kc) {
        bh[kc] = *(const bfx8*)(wb + (size_t)kc*1024);
        bl[kc] = *(const bfx8*)(wb + (size_t)kc*1024 + 512);
    }
    f32x4 acc0 = (f32x4){0.f,0.f,0.f,0.f};
    f32x4 acc1 = (f32x4){0.f,0.f,0.f,0.f};

    __syncthreads();

    const short* aph = inH + m*KS + q*8;
    const short* apl = inL + m*KS + q*8;

    #pragma unroll
    for (int kc = 0; kc < 8; ++kc) {
        const bfx8 ah = *(const bfx8*)(aph + kc*32);
        const bfx8 al = *(const bfx8*)(apl + kc*32);
        acc0 = __builtin_amdgcn_mfma_f32_16x16x32_bf16(ah, bh[kc], acc0, 0, 0, 0);
        acc1 = __builtin_amdgcn_mfma_f32_16x16x32_bf16(al, bh[kc], acc1, 0, 0, 0);
        acc1 = __builtin_amdgcn_mfma_f32_16x16x32_bf16(ah, bl[kc], acc1, 0, 0, 0);
    }
    const int cj = wid*16 + m;
    const float bv = pb2[cj];
    const float w3 = pW3[cj];
    float ps[4];
    #pragma unroll
    for (int r = 0; r < 4; ++r)
        ps[r] = fast_tanh(acc0[r] + acc1[r] + bv) * w3;
    #pragma unroll
    for (int mask = 1; mask <= 8; mask <<= 1) {
        #pragma unroll
        for (int r = 0; r < 4; ++r) ps[r] += __shfl_xor(ps[r], mask);
    }
    if (m == 0) {
        #pragma unroll
        for (int r = 0; r < 4; ++r) sPpart[wid*16 + q*4 + r] = ps[r];
    }
}

__global__ __launch_bounds__(1024, 4)
void sphere_mfma_kernel(
    const float* __restrict__ x0,  const float* __restrict__ dBt,
    const float* __restrict__ Dv,
    const short* __restrict__ pW1f, const float* __restrict__ pb1,
    const short* __restrict__ pW2f, const float* __restrict__ pb2,
    const float* __restrict__ pW3,  const float* __restrict__ pb3,
    const short* __restrict__ gW1f, const float* __restrict__ gb1,
    const short* __restrict__ gW2f, const float* __restrict__ gb2,
    const short* __restrict__ gW3f, const float* __restrict__ gb3,
    float* __restrict__ out)
{
    __shared__ short aH0[16*KS], aL0[16*KS], aH1[16*KS], aL1[16*KS];
    __shared__ short aHx[16*XKS], aLx[16*XKS];     // dedicated layer-1 x input
    __shared__ float xsF[NE*XS], gbuf[NE*XS];
    __shared__ float sPpart[NWAVE*16];
    __shared__ float sP[NE], sRun[NE], sRel[NE];

    const int tid  = threadIdx.x;
    const int lane = tid & 63, wid = tid >> 6;
    const int b0   = blockIdx.x * NE;

    // x0 -> xsF (fp32) + split-bf16 x buffer
    for (int i = tid; i < NE*96; i += 1024) {
        const int e = i / 96, k = i - e*96;
        const float v = x0[(size_t)b0*96 + i];
        xsF[e*XS + k] = v;
        short h, l; split_tr(v, h, l);
        aHx[e*XKS + k] = h;
        aLx[e*XKS + k] = l;
    }

    // ---- p0 = pMLP(x0), layer2 fused with pW3 dot ----
    layer_hidden<3, XKS>(pW1f, pb1, aHx, aLx, aH1, aL1, lane, wid);
    p_l2_dot(pW2f, pb2, pW3, aH1, aL1, sPpart, lane, wid);
    __syncthreads();
    if (tid < NE) {
        float s = pb3[0];
        #pragma unroll
        for (int w = 0; w < NWAVE; ++w) s += sPpart[w*16 + tid];
        sP[tid] = s; sRun[tid] = 1.0f; sRel[tid] = 0.0f;
    }

    const float s2d  = sqrtf(2.0f * Dv[tid & 31]);
    const float sqdt = sqrtf(0.01f);
    // particle threads are waves 8-15 (tid 512..1023): e=(tid>>5)&15, p=tid&31
    const float* dbp = (tid >= 512)
        ? dBt + (((size_t)(b0 + ((tid >> 5) & 15)))*DXP + (tid & 31))*2 : dBt;

    // ---- 100 scan steps ----
    for (int t = 0; t < NSTEPS; ++t) {
        layer_hidden<3, XKS>(gW1f + (size_t)t*49152,  gb1 + (size_t)t*256,
                             aHx, aLx, aH1, aL1, lane, wid);
        layer_hidden<8, KS>(gW2f + (size_t)t*131072, gb2 + (size_t)t*256,
                            aH1, aL1, aH0, aL0, lane, wid);

        // ===== stage 3: layer-3 MFMA (waves 0-5) || position update (waves 8-15)
        bfx8 b3h[8], b3l[8];
        float bv3 = 0.f;
        if (wid < 6) {
            const short* wb = gW3f + (size_t)t*49152 + (size_t)wid*8*1024 + lane*8;
            #pragma unroll
            for (int kc = 0; kc < 8; ++kc) {
                b3h[kc] = *(const bfx8*)(wb + (size_t)kc*1024);
                b3l[kc] = *(const bfx8*)(wb + (size_t)kc*1024 + 512);
            }
            bv3 = gb3[(size_t)t*96 + wid*16 + (lane & 15)];
        }
        float2 db = make_float2(0.f, 0.f);
        if (tid >= 512) db = *(const float2*)(dbp + (size_t)t*BATCH*DXP*2);

        __syncthreads();   // h2 (aH0) ready

        float sp=0.f, cp=0.f, sa=0.f, ca=0.f, dp0=0.f, dp1=0.f, runf=0.f;
        if (wid < 6) {
            const int m = lane & 15, q = lane >> 4;
            const short* aph = aH0 + m*KS + q*8;
            const short* apl = aL0 + m*KS + q*8;
            f32x4 acc0 = (f32x4){0.f,0.f,0.f,0.f};
            f32x4 acc1 = (f32x4){0.f,0.f,0.f,0.f};
            #pragma unroll
            for (int kc = 0; kc < 8; ++kc) {
                const bfx8 ah = *(const bfx8*)(aph + kc*32);
                const bfx8 al = *(const bfx8*)(apl + kc*32);
                acc0 = __builtin_amdgcn_mfma_f32_16x16x32_bf16(ah, b3h[kc], acc0, 0, 0, 0);
                acc1 = __builtin_amdgcn_mfma_f32_16x16x32_bf16(al, b3h[kc], acc1, 0, 0, 0);
                acc1 = __builtin_amdgcn_mfma_f32_16x16x32_bf16(ah, b3l[kc], acc1, 0, 0, 0);
            }
            const int cj = wid*16 + m;
            #pragma unroll
            for (int r = 0; r < 4; ++r)
                gbuf[(q*4 + r)*XS + cj] = acc0[r] + acc1[r] + bv3;
        } else if (tid >= 512) {
#pragma clang fp contract(off)
            const int e = (tid >> 5) & 15, p = tid & 31;
            runf = sRun[e];
            dp0 = s2d * (db.x * sqdt);
            dp1 = s2d * (db.y * sqdt);
            const float X = xsF[e*XS + 3*p + 0];
            const float Y = xsF[e*XS + 3*p + 1];
            const float Z = xsF[e*XS + 3*p + 2];
            const float zc = fminf(fmaxf(Z, -0.999999f), 0.999999f);
            ca = sqrtf(fmaxf(1.0f - zc*zc, 0.0f));   // sin(theta)
            sa = -zc;                                 // -cos(theta)
            const float rinv = rsqrtf(fmaxf(X*X + Y*Y, 1e-30f));
            cp = X * rinv;
            sp = Y * rinv;
            const float c0 = poly_cos(dp0), s0 = poly_sin(dp0);
            const float c1 = poly_cos(dp1), s1 = poly_sin(dp1);
            const float e0v = c0 * c1 - 1.0f;
            const float e1v = c0 * s1;
            const float e2v = -s0;
            const float d0 = cp*ca*e0v - sp*e1v + cp*sa*e2v;
            const float d1 = sp*ca*e0v + cp*e1v + sp*sa*e2v;
            const float d2 = -sa*e0v + ca*e2v;
            float Xn = X + runf*d0;
            float Yn = Y + runf*d1;
            float Zn = Z + runf*d2;
            Zn = (Zn < 0.f) ? -Zn : Zn;
            int   hit  = (Zn < 0.05f) ? 1 : 0;
            float psum = Xn + Yn + Zn;
            xsF[e*XS + 3*p + 0] = Xn;
            xsF[e*XS + 3*p + 1] = Yn;
            xsF[e*XS + 3*p + 2] = Zn;
            const float nv[3] = {Xn, Yn, Zn};
            #pragma unroll
            for (int c = 0; c < 3; ++c) {
                short h, l; split_tr(nv[c], h, l);
                aHx[e*XKS + 3*p + c] = h;
                aLx[e*XKS + 3*p + c] = l;
            }
            #pragma unroll
            for (int mask = 1; mask <= 16; mask <<= 1) {
                psum += __shfl_xor(psum, mask);
                hit  |= __shfl_xor(hit, mask);
            }
            if (p == 0) {
                const bool rb = runf > 0.5f;
                if (rb && hit) sRel[e] = psum / 96.0f;
                sRun[e] = (rb && !hit) ? 1.0f : 0.0f;
            }
        }

        __syncthreads();   // gbuf ready; aHx writes done

        if (tid >= 512) {
#pragma clang fp contract(off)
            const int e = (tid >> 5) & 15, p = tid & 31;
            const float g0 = gbuf[e*XS + 3*p + 0];
            const float g1 = gbuf[e*XS + 3*p + 1];
            const float g2 = gbuf[e*XS + 3*p + 2];
            const float r1  = -g0*sp + g1*cp;
            const float rr2 =  g0*cp*sa + g1*sp*sa + g2*ca;
            float dpsum = (-rr2)*dp0 + r1*dp1;
            #pragma unroll
            for (int mask = 1; mask <= 16; mask <<= 1)
                dpsum += __shfl_xor(dpsum, mask);
            if (p == 0) {
                const float pv = sP[e];
                const float dp = -(0.2f * pv) * 0.01f + dpsum;
                sP[e] = pv + dp * runf;
            }
        }
    }

    // ---- finalize ----
    __syncthreads();
    if (tid < 512) {
        const int e = tid >> 5, tt = tid & 31;
        const int b = b0 + e;
        float s = xsF[e*XS + 3*tt] + xsF[e*XS + 3*tt + 1] + xsF[e*XS + 3*tt + 2];
        #pragma unroll
        for (int mask = 1; mask <= 16; mask <<= 1) s += __shfl_xor(s, mask);
        if (tt == 0) {
            out[2*b] = sP[e];
            float pr = sRel[e];
            if (sRun[e] > 0.5f) pr = s / 96.0f;
            out[2*b + 1] = pr;
        }
    }
}

// =====================================================================
// ===================== FALLBACK (fp32, round-1) ======================
// =====================================================================
#define FNE 16
#define SH 20
#define SX 16

__device__ __forceinline__ void layer256_fb(
    int K, const float* __restrict__ W, const float* __restrict__ bias,
    const float* __restrict__ in_lds, int in_stride,
    float* __restrict__ out_lds, float* __restrict__ wbuf, int tid)
{
    const int jg = tid & 63;
    const int eg = tid >> 6;
    const int j0 = jg << 2;
    const int e0 = eg << 2;
    float acc[4][4];
    #pragma unroll
    for (int ee = 0; ee < 4; ++ee)
        #pragma unroll
        for (int jj = 0; jj < 4; ++jj) acc[ee][jj] = 0.f;
    const int nc = K >> 4;
    const float4* __restrict__ Wv = (const float4*)W;
    float4* wv = (float4*)wbuf;
    float4 pre[4];
    #pragma unroll
    for (int i = 0; i < 4; ++i) pre[i] = Wv[tid + i*256];
    for (int c = 0; c < nc; ++c) {
        __syncthreads();
        #pragma unroll
        for (int i = 0; i < 4; ++i) wv[tid + i*256] = pre[i];
        if (c + 1 < nc) {
            #pragma unroll
            for (int i = 0; i < 4; ++i) pre[i] = Wv[(c+1)*1024 + tid + i*256];
        }
        __syncthreads();
        const float* inb = in_lds + (c << 4) * in_stride + e0;
        #pragma unroll
        for (int kk = 0; kk < 16; ++kk) {
            const float4 a = *(const float4*)(inb + kk * in_stride);
            const float4 w = *(const float4*)(wbuf + kk*256 + j0);
            const float av[4] = {a.x, a.y, a.z, a.w};
            const float wl[4] = {w.x, w.y, w.z, w.w};
            #pragma unroll
            for (int ee = 0; ee < 4; ++ee)
                #pragma unroll
                for (int jj = 0; jj < 4; ++jj)
                    acc[ee][jj] += av[ee] * wl[jj];
        }
    }
    const float4 bb = *(const float4*)(bias + j0);
    const float bv[4] = {bb.x, bb.y, bb.z, bb.w};
    #pragma unroll
    for (int jj = 0; jj < 4; ++jj) {
        float4 v;
        v.x = tanhf(acc[0][jj] + bv[jj]);
        v.y = tanhf(acc[1][jj] + bv[jj]);
        v.z = tanhf(acc[2][jj] + bv[jj]);
        v.w = tanhf(acc[3][jj] + bv[jj]);
        *(float4*)(out_lds + (j0 + jj) * SH + e0) = v;
    }
}

__device__ __forceinline__ void layer3_fb(
    const float* __restrict__ W, const float* __restrict__ bias,
    const float* __restrict__ h2, float* __restrict__ wbuf,
    float* __restrict__ gbuf, int tid)
{
    const int og = tid & 31;
    const int eg = tid >> 5;
    const int o0 = og * 3;
    const int e0 = eg << 1;
    float acc[2][3];
    #pragma unroll
    for (int ee = 0; ee < 2; ++ee)
        #pragma unroll
        for (int oo = 0; oo < 3; ++oo) acc[ee][oo] = 0.f;
    const float2* __restrict__ Wv = (const float2*)W;
    float2* wv2 = (float2*)wbuf;
    float2 pre[3];
    #pragma unroll
    for (int i = 0; i < 3; ++i) pre[i] = Wv[tid + i*256];
    for (int c = 0; c < 16; ++c) {
        __syncthreads();
        #pragma unroll
        for (int i = 0; i < 3; ++i) wv2[tid + i*256] = pre[i];
        if (c + 1 < 16) {
            #pragma unroll
            for (int i = 0; i < 3; ++i) pre[i] = Wv[(c+1)*768 + tid + i*256];
        }
        __syncthreads();
        #pragma unroll
        for (int kk = 0; kk < 16; ++kk) {
            const float2 a = *(const float2*)(h2 + (c*16 + kk)*SH + e0);
            const float* wr = wbuf + kk*96 + o0;
            const float w0 = wr[0], w1 = wr[1], w2 = wr[2];
            acc[0][0] += a.x*w0; acc[0][1] += a.x*w1; acc[0][2] += a.x*w2;
            acc[1][0] += a.y*w0; acc[1][1] += a.y*w1; acc[1][2] += a.y*w2;
        }
    }
    __syncthreads();
    #pragma unroll
    for (int ee = 0; ee < 2; ++ee)
        #pragma unroll
        for (int oo = 0; oo < 3; ++oo)
            gbuf[(e0 + ee)*96 + o0 + oo] = acc[ee][oo] + bias[o0 + oo];
    __syncthreads();
}

__device__ __forceinline__ void particles_step_fb(
    int t, int b0, const float* __restrict__ dBt,
    float s2d0, float s2d1, float sqdt,
    float* __restrict__ xsT, const float* __restrict__ gbuf,
    float* __restrict__ sP, float* __restrict__ sRun, float* __restrict__ sRel,
    int tid)
{
#pragma clang fp contract(off)
    const int e  = tid >> 4;
    const int tt = tid & 15;
    const int b  = b0 + e;
    const float runf = sRun[e];
    float dpsum = 0.f, psum = 0.f;
    int hit = 0;
    #pragma unroll
    for (int pp = 0; pp < 2; ++pp) {
        const int p = tt + (pp << 4);
        const float s2d = pp ? s2d1 : s2d0;
        const float2 db = *(const float2*)(dBt + (((size_t)t*BATCH + b)*DXP + p)*2);
        const float db0 = db.x * sqdt;
        const float db1 = db.y * sqdt;
        const float dp0 = s2d * db0;
        const float dp1 = s2d * db1;
        const float X = xsT[(3*p + 0)*SX + e];
        const float Y = xsT[(3*p + 1)*SX + e];
        const float Z = xsT[(3*p + 2)*SX + e];
        const float zc = fminf(fmaxf(Z, -0.999999f), 0.999999f);
        const float theta = acosf(zc);
        const float phi = atan2f(Y, X);
        const float aa = theta - PIO2F;
        const float ca = cosf(aa), sa = sinf(aa);
        const float cp = cosf(phi), sp = sinf(phi);
        const float th = dp0 + PIO2F;
        const float st = sinf(th);
        const float e0v = st * cosf(dp1) - 1.0f;
        const float e1v = st * sinf(dp1);
        const float e2v = cosf(th);
        const float d0 = cp*ca*e0v - sp*e1v + cp*sa*e2v;
        const float d1 = sp*ca*e0v + cp*e1v + sp*sa*e2v;
        const float d2 = -sa*e0v + ca*e2v;
        float Xn = X + runf*d0;
        float Yn = Y + runf*d1;
        float Zn = Z + runf*d2;
        Zn = (Zn < 0.f) ? -Zn : Zn;
        hit |= (Zn < 0.05f) ? 1 : 0;
        psum += Xn + Yn + Zn;
        const float g0 = gbuf[e*96 + 3*p + 0];
        const float g1 = gbuf[e*96 + 3*p + 1];
        const float g2 = gbuf[e*96 + 3*p + 2];
        const float r1 = -g0*sp + g1*cp;
        const float r2 = g0*cp*sa + g1*sp*sa + g2*ca;
        dpsum += (-r2)*dp0 + r1*dp1;
        xsT[(3*p + 0)*SX + e] = Xn;
        xsT[(3*p + 1)*SX + e] = Yn;
        xsT[(3*p + 2)*SX + e] = Zn;
    }
    #pragma unroll
    for (int m = 1; m <= 8; m <<= 1) {
        dpsum += __shfl_xor(dpsum, m);
        psum  += __shfl_xor(psum, m);
        hit   |= __shfl_xor(hit, m);
    }
    if (tt == 0) {
        const float pv = sP[e];
        const float rv = sRun[e];
        const float dp = -(0.2f * pv) * 0.01f + dpsum;
        sP[e] = pv + dp * rv;
        const bool rb = rv > 0.5f;
        if (rb && hit) sRel[e] = psum / 96.0f;
        sRun[e] = (rb && !hit) ? 1.0f : 0.0f;
    }
}

__global__ __launch_bounds__(256)
void sphere_ibsde_kernel_fb(
    const float* __restrict__ x0,  const float* __restrict__ dBt,
    const float* __restrict__ Dv,
    const float* __restrict__ pW1, const float* __restrict__ pb1,
    const float* __restrict__ pW2, const float* __restrict__ pb2,
    const float* __restrict__ pW3, const float* __restrict__ pb3,
    const float* __restrict__ gW1, const float* __restrict__ gb1,
    const float* __restrict__ gW2, const float* __restrict__ gb2,
    const float* __restrict__ gW3, const float* __restrict__ gb3,
    float* __restrict__ out)
{
    __shared__ float xsT[96 * SX];
    __shared__ float h1T[256 * SH];
    __shared__ float h2T[256 * SH];
    __shared__ float wbuf[16 * 256];
    __shared__ float sP[FNE], sRun[FNE], sRel[FNE];

    const int tid = threadIdx.x;
    const int b0 = blockIdx.x * FNE;

    #pragma unroll
    for (int i = 0; i < 6; ++i) {
        const int f = tid + i*256;
        const int e = f / 96, k = f - e*96;
        xsT[k*SX + e] = x0[(size_t)b0*96 + f];
    }

    layer256_fb(96,  pW1, pb1, xsT, SX, h1T, wbuf, tid);
    layer256_fb(256, pW2, pb2, h1T, SH, h2T, wbuf, tid);
    __syncthreads();
    {
        const int e = tid >> 4, tt = tid & 15;
        float s = 0.f;
        #pragma unroll
        for (int i = 0; i < 16; ++i) {
            const int k = tt + (i << 4);
            s += h2T[k*SH + e] * pW3[k];
        }
        #pragma unroll
        for (int m = 1; m <= 8; m <<= 1) s += __shfl_xor(s, m);
        if (tt == 0) { sP[e] = s + pb3[0]; sRun[e] = 1.0f; sRel[e] = 0.0f; }
    }

    const int ttc = tid & 15;
    const float s2d0 = sqrtf(2.0f * Dv[ttc]);
    const float s2d1 = sqrtf(2.0f * Dv[ttc + 16]);
    const float sqdt = sqrtf(0.01f);

    for (int t = 0; t < NSTEPS; ++t) {
        layer256_fb(96,  gW1 + (size_t)t*96*256,  gb1 + (size_t)t*256, xsT, SX, h1T, wbuf, tid);
        layer256_fb(256, gW2 + (size_t)t*256*256, gb2 + (size_t)t*256, h1T, SH, h2T, wbuf, tid);
        layer3_fb(gW3 + (size_t)t*256*96, gb3 + (size_t)t*96, h2T, wbuf, wbuf, tid);
        particles_step_fb(t, b0, dBt, s2d0, s2d1, sqdt, xsT, wbuf, sP, sRun, sRel, tid);
    }

    __syncthreads();
    {
        const int e = tid >> 4, tt = tid & 15;
        const int b = b0 + e;
        float s = 0.f;
        #pragma unroll
        for (int i = 0; i < 6; ++i) s += xsT[(tt*6 + i)*SX + e];
        #pragma unroll
        for (int m = 1; m <= 8; m <<= 1) s += __shfl_xor(s, m);
        if (tt == 0) {
            out[2*b] = sP[e];
            float pr = sRel[e];
            if (sRun[e] > 0.5f) pr = s / 96.0f;
            out[2*b + 1] = pr;
        }
    }
}

// =====================================================================
extern "C" void kernel_launch(void* const* d_in, const int* in_sizes, int n_in,
                              void* d_out, int out_size, void* d_ws, size_t ws_size,
                              hipStream_t stream)
{
    const float* x0  = (const float*)d_in[0];
    const float* dBt = (const float*)d_in[1];
    const float* Dv  = (const float*)d_in[2];
    const float* pW1 = (const float*)d_in[3];
    const float* pb1 = (const float*)d_in[4];
    const float* pW2 = (const float*)d_in[5];
    const float* pb2 = (const float*)d_in[6];
    const float* pW3 = (const float*)d_in[7];
    const float* pb3 = (const float*)d_in[8];
    const float* gW1 = (const float*)d_in[9];
    const float* gb1 = (const float*)d_in[10];
    const float* gW2 = (const float*)d_in[11];
    const float* gb2 = (const float*)d_in[12];
    const float* gW3 = (const float*)d_in[13];
    const float* gb3 = (const float*)d_in[14];
    float* out = (float*)d_out;

    // fragment-layout sizes in shorts
    const size_t A1 = (size_t)NSTEPS * 16 * 3 * 1024;
    const size_t A2 = (size_t)NSTEPS * 16 * 8 * 1024;
    const size_t A3 = (size_t)NSTEPS *  6 * 8 * 1024;
    const size_t P1 = (size_t)16 * 3 * 1024;
    const size_t P2 = (size_t)16 * 8 * 1024;
    const size_t total_elems = A1 + A2 + A3 + P1 + P2;

    if (ws_size >= total_elems * sizeof(short)) {
        short* p = (short*)d_ws;
        short* gW1f = p;            p += A1;
        short* gW2f = p;            p += A2;
        short* gW3f = p;            p += A3;
        short* pW1f = p;            p += P1;
        short* pW2f = p;            p += P2;

        prep_frag_n256<<<dim3(NSTEPS*3*4), dim3(256), 0, stream>>>(gW1, gW1f, 96);
        prep_frag_n256<<<dim3(NSTEPS*8*4), dim3(256), 0, stream>>>(gW2, gW2f, 256);
        prep_frag_n96 <<<dim3(NSTEPS*8*4), dim3(128), 0, stream>>>(gW3, gW3f);
        prep_frag_n256<<<dim3(3*4),        dim3(256), 0, stream>>>(pW1, pW1f, 96);
        prep_frag_n256<<<dim3(8*4),        dim3(256), 0, stream>>>(pW2, pW2f, 256);

        sphere_mfma_kernel<<<dim3(BATCH / NE), dim3(1024), 0, stream>>>(
            x0, dBt, Dv,
            pW1f, pb1, pW2f, pb2, pW3, pb3,
            gW1f, gb1, gW2f, gb2, gW3f, gb3, out);
    } else {
        sphere_ibsde_kernel_fb<<<dim3(BATCH / FNE), dim3(256), 0, stream>>>(
            x0, dBt, Dv, pW1, pb1, pW2, pb2, pW3, pb3,
            gW1, gb1, gW2, gb2, gW3, gb3, out);
    }
}

// Round 8
// 762.670 us; speedup vs baseline: 1.7826x; 1.7826x over previous
//
#include <hip/hip_runtime.h>
#include <cstddef>

typedef short bfx8 __attribute__((ext_vector_type(8)));
typedef float f32x4 __attribute__((ext_vector_type(4)));

#define BATCH   4096
#define DXP     32
#define NSTEPS  100
#define NE      16      // batch elements per block
#define NWAVE   16      // waves per block (block = 1024)
#define KS      264     // A-buffer row stride (bf16 elems)
#define XS      100     // xsF/gbuf row stride in floats
#define PIO2F   1.57079632679489662f

__device__ __forceinline__ unsigned short f2bf(float v){
    unsigned u = __float_as_uint(v);
    u += 0x7FFFu + ((u >> 16) & 1u);          // RNE
    return (unsigned short)(u >> 16);
}
__device__ __forceinline__ float bf2f(unsigned short h){
    return __uint_as_float(((unsigned)h) << 16);
}
// truncation split for A: hi = top 16 bits, lo = RNE(v - hi); err ~2^-17 rel.
__device__ __forceinline__ void split_tr(float v, short& hi, short& lo){
    const unsigned u = __float_as_uint(v);
    hi = (short)(u >> 16);
    lo = (short)f2bf(v - __uint_as_float(u & 0xFFFF0000u));
}
// fast tanh (smooth p-path only)
__device__ __forceinline__ float fast_tanh(float x){
    const float e2 = __expf(2.0f * x);
    return 1.0f - __fdividef(2.0f, e2 + 1.0f);
}

// =====================================================================
// Prep: W [T][K][N] fp32 -> fragment-major SINGLE bf16 (RNE):
//   out[((t*NJ + jt)*KC + kc)*512 + (q*16+m)*8 + i]
//   n = jt*16 + m, k = kc*32 + q*8 + i. 1 KB per wave-fragment, coalesced.
// =====================================================================
__global__ __launch_bounds__(256)
void prep_frag_n256(const float* __restrict__ in, short* __restrict__ out, int K)
{
    const int KC = K >> 5;
    int b = blockIdx.x;                 // t*KC*4 + kc*4 + q
    const int q = b & 3; b >>= 2;
    const int kc = b % KC, t = b / KC;
    const int n = threadIdx.x;
    const int jt = n >> 4, m = n & 15;
    bfx8 hv;
    #pragma unroll
    for (int i = 0; i < 8; ++i) {
        const int k = kc*32 + q*8 + i;
        hv[i] = (short)f2bf(in[((size_t)t*K + k)*256 + n]);
    }
    const size_t base = ((size_t)(t*16 + jt)*KC + kc)*512 + (q*16 + m)*8;
    *(bfx8*)(out + base) = hv;
}

// N=96 (layer-3 weights), K=256, NJ=6. One block per (t,kc,q).
__global__ __launch_bounds__(128)
void prep_frag_n96(const float* __restrict__ in, short* __restrict__ out)
{
    int b = blockIdx.x;                 // t*32 + kc*4 + q
    const int q = b & 3; b >>= 2;
    const int kc = b & 7, t = b >> 3;
    const int n = threadIdx.x;
    if (n >= 96) return;
    const int jt = n >> 4, m = n & 15;
    bfx8 hv;
    #pragma unroll
    for (int i = 0; i < 8; ++i) {
        const int k = kc*32 + q*8 + i;
        hv[i] = (short)f2bf(in[((size_t)t*256 + k)*96 + n]);
    }
    const size_t base = ((size_t)(t*6 + jt)*8 + kc)*512 + (q*16 + m)*8;
    *(bfx8*)(out + base) = hv;
}

// =====================================================================
// B-fragment load (coalesced 1 KB per wave per fragment)
// =====================================================================
template<int KC>
__device__ __forceinline__ void load_B(const short* __restrict__ Wf,
                                       bfx8* bh, int lane, int wid)
{
    const short* wb = Wf + (size_t)wid*KC*512 + lane*8;
    #pragma unroll
    for (int kc = 0; kc < KC; ++kc)
        bh[kc] = *(const bfx8*)(wb + (size_t)kc*512);
}

// =====================================================================
// Hidden layer body: 16m x 256j, K = KC*32, B pre-loaded by caller.
// A = split-bf16 (2 independent MFMA chains), fast-tanh, trunc-split out.
// Wave w owns j-tile w. Internal barrier = stage entry.
// =====================================================================
template<int KC>
__device__ __forceinline__ void layer_hidden_body(
    const bfx8* bh, const float* __restrict__ bias,
    const short* __restrict__ inH, const short* __restrict__ inL,
    short* __restrict__ outH, short* __restrict__ outL,
    int lane, int wid)
{
    const int m = lane & 15, q = lane >> 4;
    const int cj = wid*16 + m;
    const float bv = bias[cj];
    f32x4 acc0 = (f32x4){0.f,0.f,0.f,0.f};
    f32x4 acc1 = (f32x4){0.f,0.f,0.f,0.f};

    __syncthreads();   // in-buffer written; out-buffer's prior readers done

    const short* aph = inH + m*KS + q*8;
    const short* apl = inL + m*KS + q*8;
    #pragma unroll
    for (int kc = 0; kc < KC; ++kc) {
        const bfx8 ah = *(const bfx8*)(aph + kc*32);
        const bfx8 al = *(const bfx8*)(apl + kc*32);
        acc0 = __builtin_amdgcn_mfma_f32_16x16x32_bf16(ah, bh[kc], acc0, 0, 0, 0);
        acc1 = __builtin_amdgcn_mfma_f32_16x16x32_bf16(al, bh[kc], acc1, 0, 0, 0);
    }
    #pragma unroll
    for (int r = 0; r < 4; ++r) {
        const float v = fast_tanh(acc0[r] + acc1[r] + bv);
        short h, l; split_tr(v, h, l);
        const int row = q*4 + r;
        outH[row*KS + cj] = h;
        outL[row*KS + cj] = l;
    }
}

// =====================================================================
// pMLP layer2 fused with pW3 dot (K=256, self-preloading).
// =====================================================================
__device__ __forceinline__ void p_l2_dot(
    const short* __restrict__ Wf,
    const float* __restrict__ pb2, const float* __restrict__ pW3,
    const short* __restrict__ inH, const short* __restrict__ inL,
    float* __restrict__ sPpart, int lane, int wid)
{
    const int m = lane & 15, q = lane >> 4;
    bfx8 bh[8];
    load_B<8>(Wf, bh, lane, wid);
    f32x4 acc0 = (f32x4){0.f,0.f,0.f,0.f};
    f32x4 acc1 = (f32x4){0.f,0.f,0.f,0.f};

    __syncthreads();

    const short* aph = inH + m*KS + q*8;
    const short* apl = inL + m*KS + q*8;
    #pragma unroll
    for (int kc = 0; kc < 8; ++kc) {
        const bfx8 ah = *(const bfx8*)(aph + kc*32);
        const bfx8 al = *(const bfx8*)(apl + kc*32);
        acc0 = __builtin_amdgcn_mfma_f32_16x16x32_bf16(ah, bh[kc], acc0, 0, 0, 0);
        acc1 = __builtin_amdgcn_mfma_f32_16x16x32_bf16(al, bh[kc], acc1, 0, 0, 0);
    }
    const int cj = wid*16 + m;
    const float bv = pb2[cj];
    const float w3 = pW3[cj];
    float ps[4];
    #pragma unroll
    for (int r = 0; r < 4; ++r)
        ps[r] = fast_tanh(acc0[r] + acc1[r] + bv) * w3;
    #pragma unroll
    for (int mask = 1; mask <= 8; mask <<= 1) {
        #pragma unroll
        for (int r = 0; r < 4; ++r) ps[r] += __shfl_xor(ps[r], mask);
    }
    if (m == 0) {
        #pragma unroll
        for (int r = 0; r < 4; ++r) sPpart[wid*16 + q*4 + r] = ps[r];
    }
}

// =====================================================================
// Particle / SDE update: 1 thread = 1 particle (tid < 512).
// EXACT round-6 math (algebraic theta/phi + libm sincos for noise) —
// trajectories bit-identical to the 828us/absmax-0.00195 run.
// =====================================================================
__device__ __forceinline__ void particles_step2(
    float2 db, float s2d, float sqdt,
    float* __restrict__ xsF, const float* __restrict__ gbuf,
    short* __restrict__ xH, short* __restrict__ xL,
    float* __restrict__ sP, float* __restrict__ sRun, float* __restrict__ sRel,
    int tid)
{
#pragma clang fp contract(off)
    const int e = tid >> 5;          // 0..15
    const int p = tid & 31;          // particle
    const float runf = sRun[e];

    const float db0 = db.x * sqdt;
    const float db1 = db.y * sqdt;
    const float dp0 = s2d * db0;
    const float dp1 = s2d * db1;
    const float X = xsF[e*XS + 3*p + 0];
    const float Y = xsF[e*XS + 3*p + 1];
    const float Z = xsF[e*XS + 3*p + 2];
    const float zc = fminf(fmaxf(Z, -0.999999f), 0.999999f);
    const float ca = sqrtf(fmaxf(1.0f - zc*zc, 0.0f));   // sin(theta)
    const float sa = -zc;                                 // -cos(theta)
    const float rinv = rsqrtf(fmaxf(X*X + Y*Y, 1e-30f));
    const float cp = X * rinv;
    const float sp = Y * rinv;
    const float c0 = cosf(dp0), s0 = sinf(dp0);
    const float c1 = cosf(dp1), s1 = sinf(dp1);
    const float e0v = c0 * c1 - 1.0f;
    const float e1v = c0 * s1;
    const float e2v = -s0;
    const float d0 = cp*ca*e0v - sp*e1v + cp*sa*e2v;
    const float d1 = sp*ca*e0v + cp*e1v + sp*sa*e2v;
    const float d2 = -sa*e0v + ca*e2v;
    float Xn = X + runf*d0;
    float Yn = Y + runf*d1;
    float Zn = Z + runf*d2;
    Zn = (Zn < 0.f) ? -Zn : Zn;
    int   hit   = (Zn < 0.05f) ? 1 : 0;
    float psum  = Xn + Yn + Zn;
    const float g0 = gbuf[e*XS + 3*p + 0];
    const float g1 = gbuf[e*XS + 3*p + 1];
    const float g2 = gbuf[e*XS + 3*p + 2];
    const float r1  = -g0*sp + g1*cp;
    const float rr2 =  g0*cp*sa + g1*sp*sa + g2*ca;
    float dpsum = (-rr2)*dp0 + r1*dp1;

    xsF[e*XS + 3*p + 0] = Xn;
    xsF[e*XS + 3*p + 1] = Yn;
    xsF[e*XS + 3*p + 2] = Zn;
    const float nv[3] = {Xn, Yn, Zn};
    #pragma unroll
    for (int c = 0; c < 3; ++c) {
        short h, l; split_tr(nv[c], h, l);
        xH[e*KS + 3*p + c] = h;
        xL[e*KS + 3*p + c] = l;
    }
    #pragma unroll
    for (int mask = 1; mask <= 16; mask <<= 1) {
        dpsum += __shfl_xor(dpsum, mask);
        psum  += __shfl_xor(psum, mask);
        hit   |= __shfl_xor(hit, mask);
    }
    if (p == 0) {
        const float pv = sP[e];
        const float dp = -(0.2f * pv) * 0.01f + dpsum;
        sP[e] = pv + dp * runf;
        const bool rb = runf > 0.5f;
        if (rb && hit) sRel[e] = psum / 96.0f;
        sRun[e] = (rb && !hit) ? 1.0f : 0.0f;
    }
}

__global__ __launch_bounds__(1024, 4)
void sphere_mfma_kernel(
    const float* __restrict__ x0,  const float* __restrict__ dBt,
    const float* __restrict__ Dv,
    const short* __restrict__ pW1f, const float* __restrict__ pb1,
    const short* __restrict__ pW2f, const float* __restrict__ pb2,
    const float* __restrict__ pW3,  const float* __restrict__ pb3,
    const short* __restrict__ gW1f, const float* __restrict__ gb1,
    const short* __restrict__ gW2f, const float* __restrict__ gb2,
    const short* __restrict__ gW3f, const float* __restrict__ gb3,
    float* __restrict__ out)
{
    __shared__ short aH0[16*KS], aL0[16*KS], aH1[16*KS], aL1[16*KS];
    __shared__ float xsF[NE*XS], gbuf[NE*XS];
    __shared__ float sPpart[NWAVE*16];
    __shared__ float sP[NE], sRun[NE], sRel[NE];

    const int tid  = threadIdx.x;
    const int lane = tid & 63, wid = tid >> 6;
    const int b0   = blockIdx.x * NE;

    // x0 -> xsF (fp32) + split-bf16 into aH0 cols 0..95 (x region)
    for (int i = tid; i < NE*96; i += 1024) {
        const int e = i / 96, k = i - e*96;
        const float v = x0[(size_t)b0*96 + i];
        xsF[e*XS + k] = v;
        short h, l; split_tr(v, h, l);
        aH0[e*KS + k] = h;
        aL0[e*KS + k] = l;
    }

    // ---- p0 = pMLP(x0), layer2 fused with pW3 dot ----
    bfx8 B1r[3];
    load_B<3>(pW1f, B1r, lane, wid);
    layer_hidden_body<3>(B1r, pb1, aH0, aL0, aH1, aL1, lane, wid);
    p_l2_dot(pW2f, pb2, pW3, aH1, aL1, sPpart, lane, wid);
    __syncthreads();
    if (tid < NE) {
        float s = pb3[0];
        #pragma unroll
        for (int w = 0; w < NWAVE; ++w) s += sPpart[w*16 + tid];
        sP[tid] = s; sRun[tid] = 1.0f; sRel[tid] = 0.0f;
    }

    const float s2d  = sqrtf(2.0f * Dv[tid & 31]);
    const float sqdt = sqrtf(0.01f);
    const float* dbp = (tid < 512)
        ? dBt + (((size_t)(b0 + (tid >> 5)))*DXP + (tid & 31))*2 : dBt;

    // preload step-0 layer-1 B (drains at first L1 barrier)
    load_B<3>(gW1f, B1r, lane, wid);

    // ---- 100 scan steps, 4 barriers each ----
    for (int t = 0; t < NSTEPS; ++t) {
        // L1: x(96) -> h1(256)
        layer_hidden_body<3>(B1r, gb1 + (size_t)t*256, aH0, aL0, aH1, aL1, lane, wid);

        // L2: h1 -> h2 (self-preloading; loads overlap L1 epilogue)
        bfx8 B2r[8];
        load_B<8>(gW2f + (size_t)t*65536, B2r, lane, wid);
        layer_hidden_body<8>(B2r, gb2 + (size_t)t*256, aH1, aL1, aH0, aL0, lane, wid);

        // L3: h2 -> g (96), waves 0-5
        bfx8 B3r[8];
        float bv3 = 0.f;
        if (wid < 6) {
            load_B<8>(gW3f + (size_t)t*24576, B3r, lane, wid);
            bv3 = gb3[(size_t)t*96 + wid*16 + (lane & 15)];
        }
        float2 db = make_float2(0.f, 0.f);
        if (tid < 512) db = *(const float2*)(dbp + (size_t)t*BATCH*DXP*2);

        __syncthreads();   // h2 (aH0) ready
        if (wid < 6) {
            const int m = lane & 15, q = lane >> 4;
            const short* aph = aH0 + m*KS + q*8;
            const short* apl = aL0 + m*KS + q*8;
            f32x4 acc0 = (f32x4){0.f,0.f,0.f,0.f};
            f32x4 acc1 = (f32x4){0.f,0.f,0.f,0.f};
            #pragma unroll
            for (int kc = 0; kc < 8; ++kc) {
                const bfx8 ah = *(const bfx8*)(aph + kc*32);
                const bfx8 al = *(const bfx8*)(apl + kc*32);
                acc0 = __builtin_amdgcn_mfma_f32_16x16x32_bf16(ah, B3r[kc], acc0, 0, 0, 0);
                acc1 = __builtin_amdgcn_mfma_f32_16x16x32_bf16(al, B3r[kc], acc1, 0, 0, 0);
            }
            const int cj = wid*16 + m;
            #pragma unroll
            for (int r = 0; r < 4; ++r)
                gbuf[(q*4 + r)*XS + cj] = acc0[r] + acc1[r] + bv3;
        }
        __syncthreads();   // gbuf ready; layer-3 done reading aH0

        // prefetch next step's L1 B now: latency overlaps particle VALU,
        // drained at next iteration's L1 barrier (not forced by a barrier here)
        if (t + 1 < NSTEPS)
            load_B<3>(gW1f + (size_t)(t+1)*24576, B1r, lane, wid);

        if (tid < 512)
            particles_step2(db, s2d, sqdt, xsF, gbuf, aH0, aL0,
                            sP, sRun, sRel, tid);
    }

    // ---- finalize ----
    __syncthreads();
    if (tid < 512) {
        const int e = tid >> 5, tt = tid & 31;
        const int b = b0 + e;
        float s = xsF[e*XS + 3*tt] + xsF[e*XS + 3*tt + 1] + xsF[e*XS + 3*tt + 2];
        #pragma unroll
        for (int mask = 1; mask <= 16; mask <<= 1) s += __shfl_xor(s, mask);
        if (tt == 0) {
            out[2*b] = sP[e];
            float pr = sRel[e];
            if (sRun[e] > 0.5f) pr = s / 96.0f;
            out[2*b + 1] = pr;
        }
    }
}

// =====================================================================
// ===================== FALLBACK (fp32, round-1) ======================
// =====================================================================
#define FNE 16
#define SH 20
#define SX 16

__device__ __forceinline__ void layer256_fb(
    int K, const float* __restrict__ W, const float* __restrict__ bias,
    const float* __restrict__ in_lds, int in_stride,
    float* __restrict__ out_lds, float* __restrict__ wbuf, int tid)
{
    const int jg = tid & 63;
    const int eg = tid >> 6;
    const int j0 = jg << 2;
    const int e0 = eg << 2;
    float acc[4][4];
    #pragma unroll
    for (int ee = 0; ee < 4; ++ee)
        #pragma unroll
        for (int jj = 0; jj < 4; ++jj) acc[ee][jj] = 0.f;
    const int nc = K >> 4;
    const float4* __restrict__ Wv = (const float4*)W;
    float4* wv = (float4*)wbuf;
    float4 pre[4];
    #pragma unroll
    for (int i = 0; i < 4; ++i) pre[i] = Wv[tid + i*256];
    for (int c = 0; c < nc; ++c) {
        __syncthreads();
        #pragma unroll
        for (int i = 0; i < 4; ++i) wv[tid + i*256] = pre[i];
        if (c + 1 < nc) {
            #pragma unroll
            for (int i = 0; i < 4; ++i) pre[i] = Wv[(c+1)*1024 + tid + i*256];
        }
        __syncthreads();
        const float* inb = in_lds + (c << 4) * in_stride + e0;
        #pragma unroll
        for (int kk = 0; kk < 16; ++kk) {
            const float4 a = *(const float4*)(inb + kk * in_stride);
            const float4 w = *(const float4*)(wbuf + kk*256 + j0);
            const float av[4] = {a.x, a.y, a.z, a.w};
            const float wl[4] = {w.x, w.y, w.z, w.w};
            #pragma unroll
            for (int ee = 0; ee < 4; ++ee)
                #pragma unroll
                for (int jj = 0; jj < 4; ++jj)
                    acc[ee][jj] += av[ee] * wl[jj];
        }
    }
    const float4 bb = *(const float4*)(bias + j0);
    const float bv[4] = {bb.x, bb.y, bb.z, bb.w};
    #pragma unroll
    for (int jj = 0; jj < 4; ++jj) {
        float4 v;
        v.x = tanhf(acc[0][jj] + bv[jj]);
        v.y = tanhf(acc[1][jj] + bv[jj]);
        v.z = tanhf(acc[2][jj] + bv[jj]);
        v.w = tanhf(acc[3][jj] + bv[jj]);
        *(float4*)(out_lds + (j0 + jj) * SH + e0) = v;
    }
}

__device__ __forceinline__ void layer3_fb(
    const float* __restrict__ W, const float* __restrict__ bias,
    const float* __restrict__ h2, float* __restrict__ wbuf,
    float* __restrict__ gbuf, int tid)
{
    const int og = tid & 31;
    const int eg = tid >> 5;
    const int o0 = og * 3;
    const int e0 = eg << 1;
    float acc[2][3];
    #pragma unroll
    for (int ee = 0; ee < 2; ++ee)
        #pragma unroll
        for (int oo = 0; oo < 3; ++oo) acc[ee][oo] = 0.f;
    const float2* __restrict__ Wv = (const float2*)W;
    float2* wv2 = (float2*)wbuf;
    float2 pre[3];
    #pragma unroll
    for (int i = 0; i < 3; ++i) pre[i] = Wv[tid + i*256];
    for (int c = 0; c < 16; ++c) {
        __syncthreads();
        #pragma unroll
        for (int i = 0; i < 3; ++i) wv2[tid + i*256] = pre[i];
        if (c + 1 < 16) {
            #pragma unroll
            for (int i = 0; i < 3; ++i) pre[i] = Wv[(c+1)*768 + tid + i*256];
        }
        __syncthreads();
        #pragma unroll
        for (int kk = 0; kk < 16; ++kk) {
            const float2 a = *(const float2*)(h2 + (c*16 + kk)*SH + e0);
            const float* wr = wbuf + kk*96 + o0;
            const float w0 = wr[0], w1 = wr[1], w2 = wr[2];
            acc[0][0] += a.x*w0; acc[0][1] += a.x*w1; acc[0][2] += a.x*w2;
            acc[1][0] += a.y*w0; acc[1][1] += a.y*w1; acc[1][2] += a.y*w2;
        }
    }
    __syncthreads();
    #pragma unroll
    for (int ee = 0; ee < 2; ++ee)
        #pragma unroll
        for (int oo = 0; oo < 3; ++oo)
            gbuf[(e0 + ee)*96 + o0 + oo] = acc[ee][oo] + bias[o0 + oo];
    __syncthreads();
}

__device__ __forceinline__ void particles_step_fb(
    int t, int b0, const float* __restrict__ dBt,
    float s2d0, float s2d1, float sqdt,
    float* __restrict__ xsT, const float* __restrict__ gbuf,
    float* __restrict__ sP, float* __restrict__ sRun, float* __restrict__ sRel,
    int tid)
{
#pragma clang fp contract(off)
    const int e  = tid >> 4;
    const int tt = tid & 15;
    const int b  = b0 + e;
    const float runf = sRun[e];
    float dpsum = 0.f, psum = 0.f;
    int hit = 0;
    #pragma unroll
    for (int pp = 0; pp < 2; ++pp) {
        const int p = tt + (pp << 4);
        const float s2d = pp ? s2d1 : s2d0;
        const float2 db = *(const float2*)(dBt + (((size_t)t*BATCH + b)*DXP + p)*2);
        const float db0 = db.x * sqdt;
        const float db1 = db.y * sqdt;
        const float dp0 = s2d * db0;
        const float dp1 = s2d * db1;
        const float X = xsT[(3*p + 0)*SX + e];
        const float Y = xsT[(3*p + 1)*SX + e];
        const float Z = xsT[(3*p + 2)*SX + e];
        const float zc = fminf(fmaxf(Z, -0.999999f), 0.999999f);
        const float theta = acosf(zc);
        const float phi = atan2f(Y, X);
        const float aa = theta - PIO2F;
        const float ca = cosf(aa), sa = sinf(aa);
        const float cp = cosf(phi), sp = sinf(phi);
        const float th = dp0 + PIO2F;
        const float st = sinf(th);
        const float e0v = st * cosf(dp1) - 1.0f;
        const float e1v = st * sinf(dp1);
        const float e2v = cosf(th);
        const float d0 = cp*ca*e0v - sp*e1v + cp*sa*e2v;
        const float d1 = sp*ca*e0v + cp*e1v + sp*sa*e2v;
        const float d2 = -sa*e0v + ca*e2v;
        float Xn = X + runf*d0;
        float Yn = Y + runf*d1;
        float Zn = Z + runf*d2;
        Zn = (Zn < 0.f) ? -Zn : Zn;
        hit |= (Zn < 0.05f) ? 1 : 0;
        psum += Xn + Yn + Zn;
        const float g0 = gbuf[e*96 + 3*p + 0];
        const float g1 = gbuf[e*96 + 3*p + 1];
        const float g2 = gbuf[e*96 + 3*p + 2];
        const float r1 = -g0*sp + g1*cp;
        const float r2 = g0*cp*sa + g1*sp*sa + g2*ca;
        dpsum += (-r2)*dp0 + r1*dp1;
        xsT[(3*p + 0)*SX + e] = Xn;
        xsT[(3*p + 1)*SX + e] = Yn;
        xsT[(3*p + 2)*SX + e] = Zn;
    }
    #pragma unroll
    for (int m = 1; m <= 8; m <<= 1) {
        dpsum += __shfl_xor(dpsum, m);
        psum  += __shfl_xor(psum, m);
        hit   |= __shfl_xor(hit, m);
    }
    if (tt == 0) {
        const float pv = sP[e];
        const float rv = sRun[e];
        const float dp = -(0.2f * pv) * 0.01f + dpsum;
        sP[e] = pv + dp * rv;
        const bool rb = rv > 0.5f;
        if (rb && hit) sRel[e] = psum / 96.0f;
        sRun[e] = (rb && !hit) ? 1.0f : 0.0f;
    }
}

__global__ __launch_bounds__(256)
void sphere_ibsde_kernel_fb(
    const float* __restrict__ x0,  const float* __restrict__ dBt,
    const float* __restrict__ Dv,
    const float* __restrict__ pW1, const float* __restrict__ pb1,
    const float* __restrict__ pW2, const float* __restrict__ pb2,
    const float* __restrict__ pW3, const float* __restrict__ pb3,
    const float* __restrict__ gW1, const float* __restrict__ gb1,
    const float* __restrict__ gW2, const float* __restrict__ gb2,
    const float* __restrict__ gW3, const float* __restrict__ gb3,
    float* __restrict__ out)
{
    __shared__ float xsT[96 * SX];
    __shared__ float h1T[256 * SH];
    __shared__ float h2T[256 * SH];
    __shared__ float wbuf[16 * 256];
    __shared__ float sP[FNE], sRun[FNE], sRel[FNE];

    const int tid = threadIdx.x;
    const int b0 = blockIdx.x * FNE;

    #pragma unroll
    for (int i = 0; i < 6; ++i) {
        const int f = tid + i*256;
        const int e = f / 96, k = f - e*96;
        xsT[k*SX + e] = x0[(size_t)b0*96 + f];
    }

    layer256_fb(96,  pW1, pb1, xsT, SX, h1T, wbuf, tid);
    layer256_fb(256, pW2, pb2, h1T, SH, h2T, wbuf, tid);
    __syncthreads();
    {
        const int e = tid >> 4, tt = tid & 15;
        float s = 0.f;
        #pragma unroll
        for (int i = 0; i < 16; ++i) {
            const int k = tt + (i << 4);
            s += h2T[k*SH + e] * pW3[k];
        }
        #pragma unroll
        for (int m = 1; m <= 8; m <<= 1) s += __shfl_xor(s, m);
        if (tt == 0) { sP[e] = s + pb3[0]; sRun[e] = 1.0f; sRel[e] = 0.0f; }
    }

    const int ttc = tid & 15;
    const float s2d0 = sqrtf(2.0f * Dv[ttc]);
    const float s2d1 = sqrtf(2.0f * Dv[ttc + 16]);
    const float sqdt = sqrtf(0.01f);

    for (int t = 0; t < NSTEPS; ++t) {
        layer256_fb(96,  gW1 + (size_t)t*96*256,  gb1 + (size_t)t*256, xsT, SX, h1T, wbuf, tid);
        layer256_fb(256, gW2 + (size_t)t*256*256, gb2 + (size_t)t*256, h1T, SH, h2T, wbuf, tid);
        layer3_fb(gW3 + (size_t)t*256*96, gb3 + (size_t)t*96, h2T, wbuf, wbuf, tid);
        particles_step_fb(t, b0, dBt, s2d0, s2d1, sqdt, xsT, wbuf, sP, sRun, sRel, tid);
    }

    __syncthreads();
    {
        const int e = tid >> 4, tt = tid & 15;
        const int b = b0 + e;
        float s = 0.f;
        #pragma unroll
        for (int i = 0; i < 6; ++i) s += xsT[(tt*6 + i)*SX + e];
        #pragma unroll
        for (int m = 1; m <= 8; m <<= 1) s += __shfl_xor(s, m);
        if (tt == 0) {
            out[2*b] = sP[e];
            float pr = sRel[e];
            if (sRun[e] > 0.5f) pr = s / 96.0f;
            out[2*b + 1] = pr;
        }
    }
}

// =====================================================================
extern "C" void kernel_launch(void* const* d_in, const int* in_sizes, int n_in,
                              void* d_out, int out_size, void* d_ws, size_t ws_size,
                              hipStream_t stream)
{
    const float* x0  = (const float*)d_in[0];
    const float* dBt = (const float*)d_in[1];
    const float* Dv  = (const float*)d_in[2];
    const float* pW1 = (const float*)d_in[3];
    const float* pb1 = (const float*)d_in[4];
    const float* pW2 = (const float*)d_in[5];
    const float* pb2 = (const float*)d_in[6];
    const float* pW3 = (const float*)d_in[7];
    const float* pb3 = (const float*)d_in[8];
    const float* gW1 = (const float*)d_in[9];
    const float* gb1 = (const float*)d_in[10];
    const float* gW2 = (const float*)d_in[11];
    const float* gb2 = (const float*)d_in[12];
    const float* gW3 = (const float*)d_in[13];
    const float* gb3 = (const float*)d_in[14];
    float* out = (float*)d_out;

    // fragment-layout sizes in shorts (single bf16)
    const size_t A1 = (size_t)NSTEPS * 16 * 3 * 512;   // 2,457,600
    const size_t A2 = (size_t)NSTEPS * 16 * 8 * 512;   // 6,553,600
    const size_t A3 = (size_t)NSTEPS *  6 * 8 * 512;   // 2,457,600
    const size_t P1 = (size_t)16 * 3 * 512;
    const size_t P2 = (size_t)16 * 8 * 512;
    const size_t total_elems = A1 + A2 + A3 + P1 + P2;

    if (ws_size >= total_elems * sizeof(short)) {
        short* p = (short*)d_ws;
        short* gW1f = p;            p += A1;
        short* gW2f = p;            p += A2;
        short* gW3f = p;            p += A3;
        short* pW1f = p;            p += P1;
        short* pW2f = p;            p += P2;

        prep_frag_n256<<<dim3(NSTEPS*3*4), dim3(256), 0, stream>>>(gW1, gW1f, 96);
        prep_frag_n256<<<dim3(NSTEPS*8*4), dim3(256), 0, stream>>>(gW2, gW2f, 256);
        prep_frag_n96 <<<dim3(NSTEPS*8*4), dim3(128), 0, stream>>>(gW3, gW3f);
        prep_frag_n256<<<dim3(3*4),        dim3(256), 0, stream>>>(pW1, pW1f, 96);
        prep_frag_n256<<<dim3(8*4),        dim3(256), 0, stream>>>(pW2, pW2f, 256);

        sphere_mfma_kernel<<<dim3(BATCH / NE), dim3(1024), 0, stream>>>(
            x0, dBt, Dv,
            pW1f, pb1, pW2f, pb2, pW3, pb3,
            gW1f, gb1, gW2f, gb2, gW3f, gb3, out);
    } else {
        sphere_ibsde_kernel_fb<<<dim3(BATCH / FNE), dim3(256), 0, stream>>>(
            x0, dBt, Dv, pW1, pb1, pW2, pb2, pW3, pb3,
            gW1, gb1, gW2, gb2, gW3, gb3, out);
    }
}